// Round 3
// baseline (1639.276 us; speedup 1.0000x reference)
//
#include <hip/hip_runtime.h>

#define BB 64
#define TT 2048
#define INW 64
#define HH 256
#define RBW 68   // 64-float k-chunk + 4 pad: chunk bases at banks {0,4,8,12}, 16B-aligned
#define IBW 20   // 16-float j-chunk + 4 pad: chunk bases at banks {0,20,8,28}, 16B-aligned

typedef float v2f __attribute__((ext_vector_type(2)));

__device__ __forceinline__ v2f fma2(v2f a, v2f b, v2f c) {
#if __has_builtin(__builtin_elementwise_fma)
    return __builtin_elementwise_fma(a, b, c);   // -> v_pk_fma_f32
#else
    v2f r; r.x = __builtin_fmaf(a.x, b.x, c.x); r.y = __builtin_fmaf(a.y, b.y, c.y); return r;
#endif
}

__device__ __forceinline__ float fast_tanh(float x) {
    // tanh(x) = 1 - 2/(e^{2x}+1); saturates correctly at +/-inf
    float e = __expf(2.0f * x);
    return 1.0f - 2.0f / (e + 1.0f);
}

// Barrier with LDS-only drain: skips the vmcnt(0) flush __syncthreads() emits,
// so u_out store-acks / I prefetches never sit on the per-step critical path.
// sched_barrier(0) stops hipcc hoisting post-barrier LDS reads (skill rule #18).
__device__ __forceinline__ void lds_barrier() {
    asm volatile("s_waitcnt lgkmcnt(0)" ::: "memory");
    __builtin_amdgcn_s_barrier();
    __builtin_amdgcn_sched_barrier(0);
}

// Intra-quad butterfly via DPP quad_perm: xor1 = [1,0,3,2] = 0xB1, xor2 = [2,3,0,1] = 0x4E.
// Pure VALU (no LDS pipe), ~4 cyc latency each.
__device__ __forceinline__ float quad_xor1(float x) {
    return __int_as_float(__builtin_amdgcn_mov_dpp(__float_as_int(x), 0xB1, 0xF, 0xF, true));
}
__device__ __forceinline__ float quad_xor2(float x) {
    return __int_as_float(__builtin_amdgcn_mov_dpp(__float_as_int(x), 0x4E, 0xF, 0xF, true));
}

// One workgroup per batch, 512 threads.
// Thread (rp = tid>>2, q = tid&3): owns W_rec rows {rp, rp+128} x k in [64q,64q+64)
// and W_in rows {rp, rp+128} x j in [16q,16q+16), all in registers (160 f32).
// Per step: 20 multicast ds_read_b128 (skewed, conflict-free) -> 80 v_pk_fma ->
// DPP quad butterfly (bit-identical to the old (p0+p1)+(p2+p3) combine) -> all 4
// lanes update u redundantly -> q==0 writes r into the OTHER r-buffer, q==1
// stores u_out. ONE lgkm-only barrier per step: the part[] LDS round-trip and
// its barrier are gone. I is prefetched 2 steps ahead into registers.
__global__ __launch_bounds__(512, 1)
void rnn_scan(const float* __restrict__ x0,
              const float* __restrict__ I,
              const float* __restrict__ W_in,
              const float* __restrict__ W_rec,
              const float* __restrict__ bias,
              float* __restrict__ u_out)
{
    __shared__ __align__(16) float rb[2][4 * RBW];     // 2.1 KB, double-buffered, skewed
    __shared__ __align__(16) float ibuf[2][4 * IBW];   // 640 B,  double-buffered, skewed

    const int b   = blockIdx.x;
    const int tid = threadIdx.x;
    const int q   = tid & 3;
    const int rp  = tid >> 2;          // [0,128)
    const int hA  = rp;
    const int hB  = rp + 128;
    const int k0  = q * 64;
    const int j0  = q * 16;

    // ---- loop-invariant weights into registers ----
    v2f wrA[32], wrB[32], wiA[8], wiB[8];
    {
        const float4* wa = (const float4*)(W_rec + (size_t)hA * HH + k0);
        const float4* wb = (const float4*)(W_rec + (size_t)hB * HH + k0);
        #pragma unroll
        for (int i = 0; i < 16; ++i) {
            float4 a = wa[i], bq = wb[i];
            wrA[2*i]     = (v2f){a.x, a.y};   wrA[2*i + 1] = (v2f){a.z, a.w};
            wrB[2*i]     = (v2f){bq.x, bq.y}; wrB[2*i + 1] = (v2f){bq.z, bq.w};
        }
        const float4* ia = (const float4*)(W_in + (size_t)hA * INW + j0);
        const float4* ib = (const float4*)(W_in + (size_t)hB * INW + j0);
        #pragma unroll
        for (int i = 0; i < 4; ++i) {
            float4 a = ia[i], bq = ib[i];
            wiA[2*i]     = (v2f){a.x, a.y};   wiA[2*i + 1] = (v2f){a.z, a.w};
            wiB[2*i]     = (v2f){bq.x, bq.y}; wiB[2*i + 1] = (v2f){bq.z, bq.w};
        }
    }

    // ---- state: u, bias held redundantly in all 4 q-lanes ----
    float uA = x0[(size_t)b * HH + hA];
    float uB = x0[(size_t)b * HH + hB];
    const float bvA = bias[hA];
    const float bvB = bias[hB];

    // r[h] lives at rb[p][RBW*(h>>6) + (h&63)]
    const int rsA = RBW * (hA >> 6) + (hA & 63);
    const int rsB = RBW * (hB >> 6) + (hB & 63);
    // I_t[j] lives at ibuf[p][IBW*(j>>4) + (j&15)]; tid<16 stages float4 j=4*tid
    const int iw  = IBW * (tid >> 2) + 4 * (tid & 3);

    if (q == 0) {
        rb[0][rsA] = fast_tanh(uA);
        rb[0][rsB] = fast_tanh(uB);
    }
    float4 i_next = {0.f, 0.f, 0.f, 0.f};
    if (tid < 16) {
        float4 i0 = ((const float4*)(I + (size_t)b * TT * INW))[tid];
        *(float4*)&ibuf[0][iw] = i0;
        i_next = ((const float4*)(I + ((size_t)b * TT + 1) * INW))[tid];  // in flight
    }
    __syncthreads();

    #pragma unroll 2
    for (int t = 0; t < TT; ++t) {
        const int p = t & 1;

        // prefetch I_{t+2} (written to LDS at the END of step t+1 -> ~1.5 steps of cover)
        float4 i_fut = {0.f, 0.f, 0.f, 0.f};
        if (tid < 16 && (t + 2) < TT)
            i_fut = ((const float4*)(I + ((size_t)b * TT + t + 2) * INW))[tid];

        // ---- partial dot: rows {rp, rp+128}, k-chunk q ----
        const float4* r4 = (const float4*)&rb[p][RBW * q];   // 4 addr streams/wave, disjoint banks
        const float4* i4 = (const float4*)&ibuf[p][IBW * q];

        v2f a0 = {0.f,0.f}, a1 = {0.f,0.f}, c0 = {0.f,0.f}, c1 = {0.f,0.f};
        #pragma unroll
        for (int i = 0; i < 16; ++i) {
            float4 r = r4[i];
            v2f r01 = (v2f){r.x, r.y}, r23 = (v2f){r.z, r.w};
            a0 = fma2(wrA[2*i],     r01, a0);
            a1 = fma2(wrA[2*i + 1], r23, a1);
            c0 = fma2(wrB[2*i],     r01, c0);
            c1 = fma2(wrB[2*i + 1], r23, c1);
        }
        #pragma unroll
        for (int i = 0; i < 4; ++i) {
            float4 r = i4[i];
            v2f r01 = (v2f){r.x, r.y}, r23 = (v2f){r.z, r.w};
            a0 = fma2(wiA[2*i],     r01, a0);
            a1 = fma2(wiA[2*i + 1], r23, a1);
            c0 = fma2(wiB[2*i],     r01, c0);
            c1 = fma2(wiB[2*i + 1], r23, c1);
        }
        v2f sA = a0 + a1, sB = c0 + c1;
        float dA = sA.x + sA.y, dB = sB.x + sB.y;

        // ---- intra-quad butterfly: all 4 lanes end with the full sum ----
        dA += quad_xor1(dA);  dB += quad_xor1(dB);
        dA += quad_xor2(dA);  dB += quad_xor2(dB);

        // ---- state update (redundant in all q-lanes; same issue cost) ----
        uA = 0.8f * uA + 0.2f * (dA + bvA);
        uB = 0.8f * uB + 0.2f * (dB + bvB);
        float rA = fast_tanh(uA), rB = fast_tanh(uB);

        if (q == 0) {                       // publish r for step t+1
            rb[p ^ 1][rsA] = rA;
            rb[p ^ 1][rsB] = rB;
        }
        if (tid < 16 && (t + 1) < TT)       // publish I_{t+1} (loaded a step ago)
            *(float4*)&ibuf[p ^ 1][iw] = i_next;
        i_next = i_fut;
        if (q == 1) {                       // stream u_out; ack never waited on
            float* uo = u_out + ((size_t)b * TT + t) * HH;
            uo[hA] = uA;
            uo[hB] = uB;
        }

        lds_barrier();                      // ONE barrier per step
    }
}

// y[b,t,o] = sum_h u[b,t,h] * Wout[o,h] + bout[o]. One wave per (b,t) row.
__global__ __launch_bounds__(256)
void readout(const float* __restrict__ u,
             const float* __restrict__ Wout,
             const float* __restrict__ bout,
             float* __restrict__ y)
{
    const int wid  = threadIdx.x >> 6;
    const int lane = threadIdx.x & 63;
    const size_t row = (size_t)blockIdx.x * 4 + wid;   // < BB*TT

    float4 uv = ((const float4*)(u + row * HH))[lane];
    float4 w0 = ((const float4*)Wout)[lane];
    float4 w1 = ((const float4*)(Wout + HH))[lane];

    float acc0 = uv.x * w0.x + uv.y * w0.y + uv.z * w0.z + uv.w * w0.w;
    float acc1 = uv.x * w1.x + uv.y * w1.y + uv.z * w1.z + uv.w * w1.w;

    #pragma unroll
    for (int m = 32; m >= 1; m >>= 1) {
        acc0 += __shfl_xor(acc0, m, 64);
        acc1 += __shfl_xor(acc1, m, 64);
    }
    if (lane == 0) {
        y[row * 2 + 0] = acc0 + bout[0];
        y[row * 2 + 1] = acc1 + bout[1];
    }
}

extern "C" void kernel_launch(void* const* d_in, const int* in_sizes, int n_in,
                              void* d_out, int out_size, void* d_ws, size_t ws_size,
                              hipStream_t stream) {
    const float* x0    = (const float*)d_in[0];
    const float* I     = (const float*)d_in[1];
    const float* W_in  = (const float*)d_in[2];
    const float* W_rec = (const float*)d_in[3];
    const float* bias  = (const float*)d_in[4];
    const float* Wout  = (const float*)d_in[5];
    const float* bout  = (const float*)d_in[6];

    float* u_out = (float*)d_out;
    float* y_out = u_out + (size_t)BB * TT * HH;

    rnn_scan<<<BB, 512, 0, stream>>>(x0, I, W_in, W_rec, bias, u_out);
    readout<<<(BB * TT) / 4, 256, 0, stream>>>(u_out, Wout, bout, y_out);
}

// Round 4
// 1552.715 us; speedup vs baseline: 1.0557x; 1.0557x over previous
//
#include <hip/hip_runtime.h>

#define BB 64
#define TT 2048
#define INW 64
#define HH 256

typedef float v2f __attribute__((ext_vector_type(2)));

__device__ __forceinline__ v2f fma2(v2f a, v2f b, v2f c) {
#if __has_builtin(__builtin_elementwise_fma)
    return __builtin_elementwise_fma(a, b, c);   // -> v_pk_fma_f32
#else
    v2f r; r.x = __builtin_fmaf(a.x, b.x, c.x); r.y = __builtin_fmaf(a.y, b.y, c.y); return r;
#endif
}

__device__ __forceinline__ float fast_tanh(float x) {
    // tanh(x) = 1 - 2/(e^{2x}+1); saturates correctly at +/-inf
    float e = __expf(2.0f * x);
    return 1.0f - 2.0f / (e + 1.0f);
}

// Barrier with LDS-only drain: skips the vmcnt(0) flush __syncthreads() emits,
// so u_out store-acks / I prefetches never sit on the per-step critical path.
// sched_barrier(0) stops hipcc hoisting post-barrier LDS reads (skill rule #18).
__device__ __forceinline__ void lds_barrier() {
    asm volatile("s_waitcnt lgkmcnt(0)" ::: "memory");
    __builtin_amdgcn_s_barrier();
    __builtin_amdgcn_sched_barrier(0);
}

// One workgroup per batch, 1024 threads (16 waves, 4/SIMD).
// Rationale: at 512 threads the allocator pinned the 160 weight floats/thread
// in AGPRs (VGPR_Count ~104 across 3 rounds, yet 160 live values + no scratch
// traffic) -> ~160 v_accvgpr_read x 2cyc per wave per step = the dominant cost.
// At 1024 threads each thread owns only 80 weight floats (2 rows x 32k + 2x8j),
// which fits the 128-arch-VGPR/wave budget (512-reg pool / 4 waves per SIMD),
// so the weights stay directly addressable by v_pk_fma.
//
// Thread (h2 = tid & 127, q = tid >> 7 in [0,8)):
//   owns W_rec rows {h2, h2+128} x k in [32q, 32q+32)
//   and  W_in  rows {h2, h2+128} x j in [8q, 8q+8).
// q is wave-uniform -> all r/i LDS reads are wave-uniform broadcasts.
// Per step: 10 ds_read_b128 -> 40 v_pk_fma -> part[q][h] -> barrier ->
// tid<256 combine 8 partials, update u, store u_out, write r_buf; wave 4
// (tids 256..319) stages I[t+1] in parallel -> barrier.
__global__ __launch_bounds__(1024, 4)
void rnn_scan(const float* __restrict__ x0,
              const float* __restrict__ I,
              const float* __restrict__ W_in,
              const float* __restrict__ W_rec,
              const float* __restrict__ bias,
              float* __restrict__ u_out)
{
    __shared__ __align__(16) float r_buf[HH];
    __shared__ __align__(16) float i_buf[INW];
    __shared__ float part[8][HH + 8];   // stride 264: 8-bank shift/row, 2-way max on reads

    const int b   = blockIdx.x;
    const int tid = threadIdx.x;
    const int h2  = tid & 127;
    const int q   = tid >> 7;          // wave-uniform (wave w has q = w>>1)
    const int k0  = q * 32;
    const int j0  = q * 8;
    const int hA  = h2;
    const int hB  = h2 + 128;
    const int il  = tid - 256;         // wave 4 lanes stage I

    // ---- loop-invariant weights into registers (80 f32 = 40 v2f) ----
    v2f wrA[16], wrB[16], wiA[4], wiB[4];
    {
        const float4* wa = (const float4*)(W_rec + (size_t)hA * HH + k0);
        const float4* wb = (const float4*)(W_rec + (size_t)hB * HH + k0);
        #pragma unroll
        for (int i = 0; i < 8; ++i) {
            float4 a = wa[i], bq = wb[i];
            wrA[2*i]     = (v2f){a.x, a.y};   wrA[2*i + 1] = (v2f){a.z, a.w};
            wrB[2*i]     = (v2f){bq.x, bq.y}; wrB[2*i + 1] = (v2f){bq.z, bq.w};
        }
        const float4* ia = (const float4*)(W_in + (size_t)hA * INW + j0);
        const float4* ib = (const float4*)(W_in + (size_t)hB * INW + j0);
        {
            float4 a = ia[0], bq = ib[0];
            wiA[0] = (v2f){a.x, a.y};   wiA[1] = (v2f){a.z, a.w};
            wiB[0] = (v2f){bq.x, bq.y}; wiB[1] = (v2f){bq.z, bq.w};
            a = ia[1]; bq = ib[1];
            wiA[2] = (v2f){a.x, a.y};   wiA[3] = (v2f){a.z, a.w};
            wiB[2] = (v2f){bq.x, bq.y}; wiB[3] = (v2f){bq.z, bq.w};
        }
    }

    // ---- state init ----
    float u = 0.0f, bv = 0.0f;
    if (tid < HH) {
        u  = x0[(size_t)b * HH + tid];
        bv = bias[tid];
        r_buf[tid] = fast_tanh(u);
    }
    if (tid < INW) i_buf[tid] = I[((size_t)b * TT + 0) * INW + tid];
    __syncthreads();

    const float4* rb4 = (const float4*)&r_buf[k0];
    const float4* ib4 = (const float4*)&i_buf[j0];

    for (int t = 0; t < TT; ++t) {
        // wave 4: prefetch next input row (overlaps the whole step)
        float i_next = 0.0f;
        if ((unsigned)il < 64u && (t + 1) < TT)
            i_next = I[((size_t)b * TT + (t + 1)) * INW + il];

        // ---- partial dot: rows {h2, h2+128}, k in [32q,32q+32) ----
        v2f aA0 = {0.f,0.f}, aA1 = {0.f,0.f}, aB0 = {0.f,0.f}, aB1 = {0.f,0.f};
        #pragma unroll
        for (int i = 0; i < 8; ++i) {
            float4 r4 = rb4[i];                      // wave-uniform -> LDS broadcast
            v2f r01 = (v2f){r4.x, r4.y}, r23 = (v2f){r4.z, r4.w};
            aA0 = fma2(wrA[2*i],     r01, aA0);
            aA1 = fma2(wrA[2*i + 1], r23, aA1);
            aB0 = fma2(wrB[2*i],     r01, aB0);
            aB1 = fma2(wrB[2*i + 1], r23, aB1);
        }
        {
            float4 r4 = ib4[0];
            v2f r01 = (v2f){r4.x, r4.y}, r23 = (v2f){r4.z, r4.w};
            aA0 = fma2(wiA[0], r01, aA0);  aA1 = fma2(wiA[1], r23, aA1);
            aB0 = fma2(wiB[0], r01, aB0);  aB1 = fma2(wiB[1], r23, aB1);
            r4 = ib4[1];
            r01 = (v2f){r4.x, r4.y}; r23 = (v2f){r4.z, r4.w};
            aA0 = fma2(wiA[2], r01, aA0);  aA1 = fma2(wiA[3], r23, aA1);
            aB0 = fma2(wiB[2], r01, aB0);  aB1 = fma2(wiB[3], r23, aB1);
        }
        v2f sA = aA0 + aA1, sB = aB0 + aB1;
        part[q][hA] = sA.x + sA.y;
        part[q][hB] = sB.x + sB.y;
        lds_barrier();                               // partials visible; r/i reads done

        if (tid < HH) {
            float d = (((part[0][tid] + part[1][tid]) + (part[2][tid] + part[3][tid])) +
                       ((part[4][tid] + part[5][tid]) + (part[6][tid] + part[7][tid]))) + bv;
            u = 0.8f * u + 0.2f * d;
            u_out[((size_t)b * TT + t) * HH + tid] = u;
            r_buf[tid] = fast_tanh(u);
        }
        if ((unsigned)il < 64u && (t + 1) < TT)      // wave 4 publishes I[t+1]
            i_buf[il] = i_next;
        lds_barrier();                               // new r/i visible for t+1
    }
}

// y[b,t,o] = sum_h u[b,t,h] * Wout[o,h] + bout[o]. One wave per (b,t) row.
__global__ __launch_bounds__(256)
void readout(const float* __restrict__ u,
             const float* __restrict__ Wout,
             const float* __restrict__ bout,
             float* __restrict__ y)
{
    const int wid  = threadIdx.x >> 6;
    const int lane = threadIdx.x & 63;
    const size_t row = (size_t)blockIdx.x * 4 + wid;   // < BB*TT

    float4 uv = ((const float4*)(u + row * HH))[lane];
    float4 w0 = ((const float4*)Wout)[lane];
    float4 w1 = ((const float4*)(Wout + HH))[lane];

    float acc0 = uv.x * w0.x + uv.y * w0.y + uv.z * w0.z + uv.w * w0.w;
    float acc1 = uv.x * w1.x + uv.y * w1.y + uv.z * w1.z + uv.w * w1.w;

    #pragma unroll
    for (int m = 32; m >= 1; m >>= 1) {
        acc0 += __shfl_xor(acc0, m, 64);
        acc1 += __shfl_xor(acc1, m, 64);
    }
    if (lane == 0) {
        y[row * 2 + 0] = acc0 + bout[0];
        y[row * 2 + 1] = acc1 + bout[1];
    }
}

extern "C" void kernel_launch(void* const* d_in, const int* in_sizes, int n_in,
                              void* d_out, int out_size, void* d_ws, size_t ws_size,
                              hipStream_t stream) {
    const float* x0    = (const float*)d_in[0];
    const float* I     = (const float*)d_in[1];
    const float* W_in  = (const float*)d_in[2];
    const float* W_rec = (const float*)d_in[3];
    const float* bias  = (const float*)d_in[4];
    const float* Wout  = (const float*)d_in[5];
    const float* bout  = (const float*)d_in[6];

    float* u_out = (float*)d_out;
    float* y_out = u_out + (size_t)BB * TT * HH;

    rnn_scan<<<BB, 1024, 0, stream>>>(x0, I, W_in, W_rec, bias, u_out);
    readout<<<(BB * TT) / 4, 256, 0, stream>>>(u_out, Wout, bout, y_out);
}